// Round 4
// baseline (1586.747 us; speedup 1.0000x reference)
//
#include <hip/hip_runtime.h>
#include <stdint.h>

#define Tt 16
#define Cc 768
#define Ss 2048          // H*W*D
#define N1 2304
#define NH 12
#define HD 64
#define EPSV 1e-6f
#define CH 256           // spatial positions per chunk
#define NCH 8            // number of chunks (CH*NCH == Ss)
#define Mc (Tt * CH)     // 4096 rows per chunk

typedef unsigned short ushort_t;
typedef __attribute__((ext_vector_type(8))) short short8;   // 8 bf16
typedef __attribute__((ext_vector_type(4))) float f32x4;

static __device__ __forceinline__ float b2f(unsigned short u) {
  union { unsigned int i; float f; } c;
  c.i = ((unsigned int)u) << 16;
  return c.f;
}
static __device__ __forceinline__ unsigned short f2b(float f) {
  union { float f; unsigned int i; } c;
  c.f = f;
  return (unsigned short)((c.i + 0x7fffu + ((c.i >> 16) & 1u)) >> 16);
}

// dual-dtype loaders: flag==1 -> input buffer is float32, else bf16
static __device__ __forceinline__ void load8(const void* p, size_t eoff,
                                             int isf32, float* o) {
  if (isf32) {
    const float* f = (const float*)p + eoff;
    f32x4 a = *(const f32x4*)f;
    f32x4 b = *(const f32x4*)(f + 4);
    o[0] = a[0]; o[1] = a[1]; o[2] = a[2]; o[3] = a[3];
    o[4] = b[0]; o[5] = b[1]; o[6] = b[2]; o[7] = b[3];
  } else {
    short8 d = *(const short8*)((const ushort_t*)p + eoff);
#pragma unroll
    for (int e = 0; e < 8; e++) o[e] = b2f((unsigned short)d[e]);
  }
}
static __device__ __forceinline__ float load1(const void* p, size_t eoff, int isf32) {
  return isf32 ? ((const float*)p)[eoff] : b2f(((const ushort_t*)p)[eoff]);
}

// ---------------------------------------------------------------- kernel 0
// dtype detector: f32 data read as bf16 pairs shows exponent-0xFF patterns
// (~1/256 of low-halves); true bf16 normal data never does.
__global__ __launch_bounds__(256) void detect_k(const ushort_t* __restrict__ x,
                                               int* __restrict__ flag) {
  __shared__ int sbad;
  if (threadIdx.x == 0) sbad = 0;
  __syncthreads();
  int bad = 0;
  for (int i = threadIdx.x; i < 65536; i += 256) {
    const unsigned int e = (x[i] >> 7) & 0xFFu;
    if (e == 0xFFu) bad = 1;
  }
  if (bad) atomicOr(&sbad, 1);
  __syncthreads();
  if (threadIdx.x == 0) flag[0] = sbad;
}

// ---------------------------------------------------------------- kernel 0b
// convert big weight buffers to bf16 (or copy if already bf16)
__global__ __launch_bounds__(256) void cvt_big_k(const void* __restrict__ src,
                                                ushort_t* __restrict__ dst,
                                                int n8, const int* __restrict__ flag) {
  const int isf32 = *flag;
  const int i = blockIdx.x * 256 + threadIdx.x;
  if (i >= n8) return;
  float o[8];
  load8(src, (size_t)i * 8, isf32, o);
  short8 v;
#pragma unroll
  for (int e = 0; e < 8; e++) v[e] = (short)f2b(o[e]);
  *(short8*)(dst + (size_t)i * 8) = v;
}

// small-weights pack: w1[768] bin[2304] bo[768] qs[64] qb[64] ks[64] kb[64] relb[384]
__global__ __launch_bounds__(256) void cvt_small_k(
    const void* w1, const void* bin, const void* bo, const void* qs,
    const void* qb, const void* ks, const void* kb, const void* relb,
    ushort_t* __restrict__ dst, const int* __restrict__ flag) {
  const int isf32 = *flag;
  const void* srcs[8] = {w1, bin, bo, qs, qb, ks, kb, relb};
  const int sizes[8] = {768, 2304, 768, 64, 64, 64, 64, 384};
  int off = 0;
#pragma unroll
  for (int s = 0; s < 8; s++) {
    for (int i = threadIdx.x; i < sizes[s]; i += 256)
      dst[off + i] = isf32 ? f2b(((const float*)srcs[s])[i])
                           : ((const ushort_t*)srcs[s])[i];
    off += sizes[s];
  }
}

// ---------------------------------------------------------------- kernel 1
// group-RMS statistics: one block per (t, group); 64ch x 2048 spatial each
__global__ __launch_bounds__(256) void rms_stats_k(
    const void* __restrict__ x, const int* __restrict__ flag,
    float* __restrict__ invrms) {
  const int isf32 = *flag;
  const int t = blockIdx.x / NH;
  const int g = blockIdx.x % NH;
  const size_t base = ((size_t)(t * Cc + g * 64)) * Ss;
  float ss = 0.f;
  for (int v = threadIdx.x; v < 16384; v += 256) {
    const int ci = v >> 8;
    const int sj = (v & 255) << 3;
    float o[8];
    load8(x, base + (size_t)ci * Ss + sj, isf32, o);
#pragma unroll
    for (int e = 0; e < 8; e++) ss += o[e] * o[e];
  }
#pragma unroll
  for (int m = 1; m < 64; m <<= 1) ss += __shfl_xor(ss, m);
  __shared__ float red[4];
  if ((threadIdx.x & 63) == 0) red[threadIdx.x >> 6] = ss;
  __syncthreads();
  if (threadIdx.x == 0) {
    float tot = red[0] + red[1] + red[2] + red[3];
    invrms[blockIdx.x] = rsqrtf(tot * (1.f / 131072.f) + EPSV);
  }
}

// ---------------------------------------------------------------- kernel 2
// chunk-local norm+transpose:
// xnc[r=(t*CH+sl)][c] = x[t][c][s0c+sl] * invrms[t][c/64] * w1[c]
__global__ __launch_bounds__(256) void norm_chunk_k(
    const void* __restrict__ x, const int* __restrict__ flag,
    const ushort_t* __restrict__ w1, const float* __restrict__ invrms,
    ushort_t* __restrict__ xnc, int s0c) {
  __shared__ __align__(16) ushort_t tile[64][64];
  const int isf32 = *flag;
  const int t = blockIdx.z;
  const int c0 = blockIdx.y * 64;
  const int sl0 = blockIdx.x * 64;
  const float ir = invrms[t * NH + (c0 >> 6)];
  const int tid = threadIdx.x;
  for (int v = tid; v < 512; v += 256) {
    const int ci = v >> 3;
    const int q = v & 7;
    float o[8];
    load8(x, ((size_t)(t * Cc + c0 + ci)) * Ss + s0c + sl0 + q * 8, isf32, o);
    const float sc = ir * b2f(w1[c0 + ci]);
    short8 w;
#pragma unroll
    for (int e = 0; e < 8; e++) w[e] = (short)f2b(o[e] * sc);
    *(short8*)&tile[ci][(q ^ (ci >> 3)) * 8] = w;
  }
  __syncthreads();
  for (int v = tid; v < 512; v += 256) {
    const int sj = v >> 3;
    const int cb = (v & 7) * 8;
    const int sw = (sj >> 3) ^ (v & 7);
    const int so = sj & 7;
    short8 o;
#pragma unroll
    for (int e = 0; e < 8; e++) o[e] = (short)tile[cb + e][sw * 8 + so];
    *(short8*)(xnc + ((size_t)(t * CH + sl0 + sj)) * Cc + c0 + cb) = o;
  }
}

// ---------------------------------------------------------------- kernel 3
// qkvc[r][o] = xnc[r][:] . win[o][:] + bin[o]; 128x128 tile, BK=32
__global__ __launch_bounds__(256, 2) void gemm_qkv_k(
    const ushort_t* __restrict__ A, const ushort_t* __restrict__ Bw,
    const ushort_t* __restrict__ bias, ushort_t* __restrict__ Cout) {
  __shared__ __align__(16) ushort_t As[128 * 32];
  __shared__ __align__(16) ushort_t Bs[128 * 32];
  const int tid = threadIdx.x;
  const int bm0 = blockIdx.x * 128;
  const int bn0 = blockIdx.y * 128;
  const int lane = tid & 63;
  const int wave = tid >> 6;
  const int wm = (wave >> 1) << 6;
  const int wn = (wave & 1) << 6;
  f32x4 acc[4][4];
#pragma unroll
  for (int i = 0; i < 4; i++)
#pragma unroll
    for (int j = 0; j < 4; j++) acc[i][j] = (f32x4){0.f, 0.f, 0.f, 0.f};
  const int srow = tid >> 2;
  const int scol = (tid & 3) << 3;
  const ushort_t* ag = A + (size_t)(bm0 + srow) * Cc + scol;
  const ushort_t* bg = Bw + (size_t)(bn0 + srow) * Cc + scol;
  const int frow = lane & 15;
  const int koff = (lane >> 4) << 3;
  for (int kt = 0; kt < Cc; kt += 32) {
    short8 a0 = *(const short8*)(ag + kt);
    short8 a1 = *(const short8*)(ag + kt + 64 * Cc);
    short8 b0 = *(const short8*)(bg + kt);
    short8 b1 = *(const short8*)(bg + kt + 64 * Cc);
    __syncthreads();
    *(short8*)(As + tid * 8) = a0;
    *(short8*)(As + 2048 + tid * 8) = a1;
    *(short8*)(Bs + tid * 8) = b0;
    *(short8*)(Bs + 2048 + tid * 8) = b1;
    __syncthreads();
    short8 af[4], bf[4];
#pragma unroll
    for (int i = 0; i < 4; i++)
      af[i] = *(const short8*)(As + (wm + i * 16 + frow) * 32 + koff);
#pragma unroll
    for (int j = 0; j < 4; j++)
      bf[j] = *(const short8*)(Bs + (wn + j * 16 + frow) * 32 + koff);
#pragma unroll
    for (int i = 0; i < 4; i++)
#pragma unroll
      for (int j = 0; j < 4; j++)
        acc[i][j] = __builtin_amdgcn_mfma_f32_16x16x32_bf16(af[i], bf[j], acc[i][j], 0, 0, 0);
  }
  const int mq = (lane >> 4) << 2;
  const int nl = lane & 15;
#pragma unroll
  for (int j = 0; j < 4; j++) {
    const int col = bn0 + wn + j * 16 + nl;
    const float bc = b2f(bias[col]);
#pragma unroll
    for (int i = 0; i < 4; i++) {
#pragma unroll
      for (int r = 0; r < 4; r++) {
        const int row = bm0 + wm + i * 16 + mq + r;
        Cout[(size_t)row * N1 + col] = f2b(acc[i][j][r] + bc);
      }
    }
  }
}

// ---------------------------------------------------------------- kernel 4
// per chunk-local spatial sl: 12 heads of (layernorm q,k -> 16x16 softmax
// with T5 relative bias -> PV), aoc[r=(t*CH+sl)][c=h*64+j]
__global__ __launch_bounds__(256) void attention_k(
    const ushort_t* __restrict__ qkvc, const ushort_t* __restrict__ qs,
    const ushort_t* __restrict__ qb, const ushort_t* __restrict__ ks,
    const ushort_t* __restrict__ kb, const ushort_t* __restrict__ relb,
    ushort_t* __restrict__ aoc) {
  __shared__ float qf[16][68], kf[16][68], vf[16][68];
  __shared__ float attw[16][17];
  const int sl = blockIdx.x;
  const int tid = threadIdx.x;
  const int lane = tid & 63;
  const int wave = tid >> 6;
  for (int h = 0; h < NH; h++) {
    for (int e = tid; e < 3072; e += 256) {
      const int t = e / 192;
      const int j = e - t * 192;
      const float val = b2f(qkvc[((size_t)(t * CH + sl)) * N1 + h * 192 + j]);
      if (j < 64) qf[t][j] = val;
      else if (j < 128) kf[t][j - 64] = val;
      else vf[t][j - 128] = val;
    }
    __syncthreads();
#pragma unroll
    for (int r = 0; r < 8; r++) {
      const int row = wave * 8 + r;
      float* buf = (row < 16) ? &qf[row][0] : &kf[row - 16][0];
      const ushort_t* scp = (row < 16) ? qs : ks;
      const ushort_t* bip = (row < 16) ? qb : kb;
      float v = buf[lane];
      float mu = v;
#pragma unroll
      for (int m = 1; m < 64; m <<= 1) mu += __shfl_xor(mu, m);
      mu *= (1.f / 64.f);
      const float d = v - mu;
      float var = d * d;
#pragma unroll
      for (int m = 1; m < 64; m <<= 1) var += __shfl_xor(var, m);
      var *= (1.f / 64.f);
      buf[lane] = d * rsqrtf(var + EPSV) * b2f(scp[lane]) + b2f(bip[lane]);
    }
    __syncthreads();
    {
      const int t1 = tid >> 4;
      const int t2 = tid & 15;
      float sco = 0.f;
#pragma unroll
      for (int j = 0; j < 64; j++) sco += qf[t1][j] * kf[t2][j];
      const int rp = t2 - t1;
      int bkt = (rp > 0) ? 16 : 0;
      const int n = (rp < 0) ? -rp : rp;
      if (n < 8) {
        bkt += n;
      } else {
        int vl = 8 + (int)(__logf((float)n * 0.125f) * 2.8853900817779268f);
        bkt += (vl < 15) ? vl : 15;
      }
      sco = sco * 0.125f + b2f(relb[bkt * NH + h]);
      float mx = sco;
#pragma unroll
      for (int m = 8; m >= 1; m >>= 1) mx = fmaxf(mx, __shfl_xor(mx, m));
      const float ex = __expf(sco - mx);
      float sm = ex;
#pragma unroll
      for (int m = 8; m >= 1; m >>= 1) sm += __shfl_xor(sm, m);
      attw[t1][t2] = ex / sm;
    }
    __syncthreads();
    for (int e = tid; e < 1024; e += 256) {
      const int t1 = e >> 6;
      const int j = e & 63;
      float o = 0.f;
#pragma unroll
      for (int t = 0; t < 16; t++) o += attw[t1][t] * vf[t][j];
      aoc[((size_t)(t1 * CH + sl)) * Cc + h * HD + j] = f2b(o);
    }
    __syncthreads();
  }
}

// ---------------------------------------------------------------- kernel 5
// D[c_out][r] = wo[c_out][:] . aoc[r][:]; writes y[t][c_out][s0c+sl] as
// FLOAT32 (reference output dtype), fused +bias +residual
__global__ __launch_bounds__(256, 2) void gemm_out_k(
    const ushort_t* __restrict__ A, const ushort_t* __restrict__ Bm,
    const ushort_t* __restrict__ bias, const void* __restrict__ xres,
    const int* __restrict__ flag, float* __restrict__ y, int s0c) {
  __shared__ __align__(16) ushort_t As[128 * 32];
  __shared__ __align__(16) ushort_t Bs[128 * 32];
  const int isf32 = *flag;
  const int tid = threadIdx.x;
  const int bm0 = blockIdx.x * 128;  // c_out
  const int bn0 = blockIdx.y * 128;  // r (chunk row)
  const int lane = tid & 63;
  const int wave = tid >> 6;
  const int wm = (wave >> 1) << 6;
  const int wn = (wave & 1) << 6;
  f32x4 acc[4][4];
#pragma unroll
  for (int i = 0; i < 4; i++)
#pragma unroll
    for (int j = 0; j < 4; j++) acc[i][j] = (f32x4){0.f, 0.f, 0.f, 0.f};
  const int srow = tid >> 2;
  const int scol = (tid & 3) << 3;
  const ushort_t* ag = A + (size_t)(bm0 + srow) * Cc + scol;
  const ushort_t* bg = Bm + (size_t)(bn0 + srow) * Cc + scol;
  const int frow = lane & 15;
  const int koff = (lane >> 4) << 3;
  for (int kt = 0; kt < Cc; kt += 32) {
    short8 a0 = *(const short8*)(ag + kt);
    short8 a1 = *(const short8*)(ag + kt + 64 * Cc);
    short8 b0 = *(const short8*)(bg + kt);
    short8 b1 = *(const short8*)(bg + kt + 64 * Cc);
    __syncthreads();
    *(short8*)(As + tid * 8) = a0;
    *(short8*)(As + 2048 + tid * 8) = a1;
    *(short8*)(Bs + tid * 8) = b0;
    *(short8*)(Bs + 2048 + tid * 8) = b1;
    __syncthreads();
    short8 af[4], bf[4];
#pragma unroll
    for (int i = 0; i < 4; i++)
      af[i] = *(const short8*)(As + (wm + i * 16 + frow) * 32 + koff);
#pragma unroll
    for (int j = 0; j < 4; j++)
      bf[j] = *(const short8*)(Bs + (wn + j * 16 + frow) * 32 + koff);
#pragma unroll
    for (int i = 0; i < 4; i++)
#pragma unroll
      for (int j = 0; j < 4; j++)
        acc[i][j] = __builtin_amdgcn_mfma_f32_16x16x32_bf16(af[i], bf[j], acc[i][j], 0, 0, 0);
  }
  const int mq = (lane >> 4) << 2;
  const int nl = lane & 15;
#pragma unroll
  for (int j = 0; j < 4; j++) {
    const int col = bn0 + wn + j * 16 + nl;  // chunk row r
    const int t = col >> 8;                  // r / CH
    const int sp = s0c + (col & (CH - 1));   // global spatial
#pragma unroll
    for (int i = 0; i < 4; i++) {
#pragma unroll
      for (int r = 0; r < 4; r++) {
        const int cch = bm0 + wm + i * 16 + mq + r;  // c_out
        const size_t off = ((size_t)(t * Cc + cch)) * Ss + sp;
        y[off] = acc[i][j][r] + b2f(bias[cch]) + load1(xres, off, isf32);
      }
    }
  }
}

// ----------------------------------------------------------------
extern "C" void kernel_launch(void* const* d_in, const int* in_sizes, int n_in,
                              void* d_out, int out_size, void* d_ws, size_t ws_size,
                              hipStream_t stream) {
  (void)in_sizes; (void)n_in; (void)out_size; (void)ws_size;
  const void* x   = d_in[0];
  const void* w1  = d_in[1];
  const void* win = d_in[2];
  const void* bin = d_in[3];
  const void* qsc = d_in[4];
  const void* qbi = d_in[5];
  const void* ksc = d_in[6];
  const void* kbi = d_in[7];
  const void* rbt = d_in[8];
  const void* wo  = d_in[9];
  const void* bo  = d_in[10];
  float* y = (float*)d_out;   // reference output dtype = float32

  // ws layout (bytes, 1KB-aligned): flag | invrms | smallw | winb | wob |
  //                                 xnc | qkvc | aoc          (~34.5 MB)
  char* ws = (char*)d_ws;
  int* flag      = (int*)ws;
  float* invrms  = (float*)(ws + 1024);
  ushort_t* smallw = (ushort_t*)(ws + 4096);
  // smallw elem offsets: w1 0 | bin 768 | bo 3072 | qs 3840 | qb 3904 |
  //                      ks 3968 | kb 4032 | relb 4096   (4480 total)
  ushort_t* w1b  = smallw;
  ushort_t* binb = smallw + 768;
  ushort_t* bob  = smallw + 3072;
  ushort_t* qsb  = smallw + 3840;
  ushort_t* qbb  = smallw + 3904;
  ushort_t* ksb  = smallw + 3968;
  ushort_t* kbb  = smallw + 4032;
  ushort_t* relbb = smallw + 4096;
  ushort_t* winb = (ushort_t*)(ws + 20480);
  ushort_t* wob  = (ushort_t*)(ws + 3559424);
  ushort_t* xnc  = (ushort_t*)(ws + 4739072);
  ushort_t* qkvc = (ushort_t*)(ws + 11030528);
  ushort_t* aoc  = (ushort_t*)(ws + 29904896);

  detect_k<<<1, 256, 0, stream>>>((const ushort_t*)x, flag);
  cvt_small_k<<<1, 256, 0, stream>>>(w1, bin, bo, qsc, qbi, ksc, kbi, rbt, smallw, flag);
  cvt_big_k<<<1769472 / 8 / 256, 256, 0, stream>>>(win, winb, 1769472 / 8, flag);
  cvt_big_k<<<589824 / 8 / 256, 256, 0, stream>>>(wo, wob, 589824 / 8, flag);
  rms_stats_k<<<dim3(Tt * NH), 256, 0, stream>>>(x, flag, invrms);
  for (int c8 = 0; c8 < NCH; c8++) {
    const int s0c = c8 * CH;
    norm_chunk_k<<<dim3(CH / 64, Cc / 64, Tt), 256, 0, stream>>>(x, flag, w1b, invrms, xnc, s0c);
    gemm_qkv_k<<<dim3(Mc / 128, N1 / 128), 256, 0, stream>>>(xnc, winb, binb, qkvc);
    attention_k<<<dim3(CH), 256, 0, stream>>>(qkvc, qsb, qbb, ksb, kbb, relbb, aoc);
    gemm_out_k<<<dim3(Cc / 128, Mc / 128), 256, 0, stream>>>(wob, aoc, bob, x, flag, y, s0c);
  }
}

// Round 5
// 912.476 us; speedup vs baseline: 1.7389x; 1.7389x over previous
//
#include <hip/hip_runtime.h>
#include <stdint.h>

#define Tt 16
#define Cc 768
#define Ss 2048          // H*W*D
#define N1 2304
#define NH 12
#define HD 64
#define EPSV 1e-6f
#define CH 256           // spatial positions per chunk
#define NCH 8            // number of chunks (CH*NCH == Ss)
#define Mc (Tt * CH)     // 4096 rows per chunk

typedef unsigned short ushort_t;
typedef __attribute__((ext_vector_type(8))) short short8;   // 8 bf16
typedef __attribute__((ext_vector_type(4))) short short4v;  // 4 bf16
typedef __attribute__((ext_vector_type(4))) float f32x4;

static __device__ __forceinline__ float b2f(unsigned short u) {
  union { unsigned int i; float f; } c;
  c.i = ((unsigned int)u) << 16;
  return c.f;
}
static __device__ __forceinline__ unsigned short f2b(float f) {
  union { float f; unsigned int i; } c;
  c.f = f;
  return (unsigned short)((c.i + 0x7fffu + ((c.i >> 16) & 1u)) >> 16);
}

// dual-dtype loaders: flag==1 -> input buffer is float32, else bf16
static __device__ __forceinline__ void load8(const void* p, size_t eoff,
                                             int isf32, float* o) {
  if (isf32) {
    const float* f = (const float*)p + eoff;
    f32x4 a = *(const f32x4*)f;
    f32x4 b = *(const f32x4*)(f + 4);
    o[0] = a[0]; o[1] = a[1]; o[2] = a[2]; o[3] = a[3];
    o[4] = b[0]; o[5] = b[1]; o[6] = b[2]; o[7] = b[3];
  } else {
    short8 d = *(const short8*)((const ushort_t*)p + eoff);
#pragma unroll
    for (int e = 0; e < 8; e++) o[e] = b2f((unsigned short)d[e]);
  }
}
static __device__ __forceinline__ float load1(const void* p, size_t eoff, int isf32) {
  return isf32 ? ((const float*)p)[eoff] : b2f(((const ushort_t*)p)[eoff]);
}

#define GLP(p) ((const __attribute__((address_space(1))) void*)(p))
#define LDSP(p) ((__attribute__((address_space(3))) void*)(p))

// ---------------------------------------------------------------- kernel 0
__global__ __launch_bounds__(256) void detect_k(const ushort_t* __restrict__ x,
                                               int* __restrict__ flag) {
  __shared__ int sbad;
  if (threadIdx.x == 0) sbad = 0;
  __syncthreads();
  int bad = 0;
  for (int i = threadIdx.x; i < 65536; i += 256) {
    const unsigned int e = (x[i] >> 7) & 0xFFu;
    if (e == 0xFFu) bad = 1;
  }
  if (bad) atomicOr(&sbad, 1);
  __syncthreads();
  if (threadIdx.x == 0) flag[0] = sbad;
}

// ---------------------------------------------------------------- kernel 0b
__global__ __launch_bounds__(256) void cvt_big_k(const void* __restrict__ src,
                                                ushort_t* __restrict__ dst,
                                                int n8, const int* __restrict__ flag) {
  const int isf32 = *flag;
  const int i = blockIdx.x * 256 + threadIdx.x;
  if (i >= n8) return;
  float o[8];
  load8(src, (size_t)i * 8, isf32, o);
  short8 v;
#pragma unroll
  for (int e = 0; e < 8; e++) v[e] = (short)f2b(o[e]);
  *(short8*)(dst + (size_t)i * 8) = v;
}

__global__ __launch_bounds__(256) void cvt_small_k(
    const void* w1, const void* bin, const void* bo, const void* qs,
    const void* qb, const void* ks, const void* kb, const void* relb,
    ushort_t* __restrict__ dst, const int* __restrict__ flag) {
  const int isf32 = *flag;
  const void* srcs[8] = {w1, bin, bo, qs, qb, ks, kb, relb};
  const int sizes[8] = {768, 2304, 768, 64, 64, 64, 64, 384};
  int off = 0;
#pragma unroll
  for (int s = 0; s < 8; s++) {
    for (int i = threadIdx.x; i < sizes[s]; i += 256)
      dst[off + i] = isf32 ? f2b(((const float*)srcs[s])[i])
                           : ((const ushort_t*)srcs[s])[i];
    off += sizes[s];
  }
}

// ---------------------------------------------------------------- kernel 1
__global__ __launch_bounds__(256) void rms_stats_k(
    const void* __restrict__ x, const int* __restrict__ flag,
    float* __restrict__ invrms) {
  const int isf32 = *flag;
  const int t = blockIdx.x / NH;
  const int g = blockIdx.x % NH;
  const size_t base = ((size_t)(t * Cc + g * 64)) * Ss;
  float ss = 0.f;
  for (int v = threadIdx.x; v < 16384; v += 256) {
    const int ci = v >> 8;
    const int sj = (v & 255) << 3;
    float o[8];
    load8(x, base + (size_t)ci * Ss + sj, isf32, o);
#pragma unroll
    for (int e = 0; e < 8; e++) ss += o[e] * o[e];
  }
#pragma unroll
  for (int m = 1; m < 64; m <<= 1) ss += __shfl_xor(ss, m);
  __shared__ float red[4];
  if ((threadIdx.x & 63) == 0) red[threadIdx.x >> 6] = ss;
  __syncthreads();
  if (threadIdx.x == 0) {
    float tot = red[0] + red[1] + red[2] + red[3];
    invrms[blockIdx.x] = rsqrtf(tot * (1.f / 131072.f) + EPSV);
  }
}

// ---------------------------------------------------------------- kernel 2
__global__ __launch_bounds__(256) void norm_chunk_k(
    const void* __restrict__ x, const int* __restrict__ flag,
    const ushort_t* __restrict__ w1, const float* __restrict__ invrms,
    ushort_t* __restrict__ xnc, int s0c) {
  __shared__ __align__(16) ushort_t tile[64][64];
  const int isf32 = *flag;
  const int t = blockIdx.z;
  const int c0 = blockIdx.y * 64;
  const int sl0 = blockIdx.x * 64;
  const float ir = invrms[t * NH + (c0 >> 6)];
  const int tid = threadIdx.x;
  for (int v = tid; v < 512; v += 256) {
    const int ci = v >> 3;
    const int q = v & 7;
    float o[8];
    load8(x, ((size_t)(t * Cc + c0 + ci)) * Ss + s0c + sl0 + q * 8, isf32, o);
    const float sc = ir * b2f(w1[c0 + ci]);
    short8 w;
#pragma unroll
    for (int e = 0; e < 8; e++) w[e] = (short)f2b(o[e] * sc);
    *(short8*)&tile[ci][(q ^ (ci >> 3)) * 8] = w;
  }
  __syncthreads();
  for (int v = tid; v < 512; v += 256) {
    const int sj = v >> 3;
    const int cb = (v & 7) * 8;
    const int sw = (sj >> 3) ^ (v & 7);
    const int so = sj & 7;
    short8 o;
#pragma unroll
    for (int e = 0; e < 8; e++) o[e] = (short)tile[cb + e][sw * 8 + so];
    *(short8*)(xnc + ((size_t)(t * CH + sl0 + sj)) * Cc + c0 + cb) = o;
  }
}

// ---------------------------------------------------------------- kernel 3
// qkvc[r][o] = xnc[r][:] . win[o][:] + bin[o]; 128x128 tile, BK=32,
// global_load_lds width=16 staging (m97 pattern)
__global__ __launch_bounds__(256, 2) void gemm_qkv_k(
    const ushort_t* __restrict__ A, const ushort_t* __restrict__ Bw,
    const ushort_t* __restrict__ bias, ushort_t* __restrict__ Cout) {
  __shared__ __align__(16) ushort_t As[128 * 32];
  __shared__ __align__(16) ushort_t Bs[128 * 32];
  const int tid = threadIdx.x;
  const int bm0 = blockIdx.x * 128;
  const int bn0 = blockIdx.y * 128;
  const int lane = tid & 63;
  const int wave = tid >> 6;
  const int wm = (wave >> 1) << 6;
  const int wn = (wave & 1) << 6;
  f32x4 acc[4][4];
#pragma unroll
  for (int i = 0; i < 4; i++)
#pragma unroll
    for (int j = 0; j < 4; j++) acc[i][j] = (f32x4){0.f, 0.f, 0.f, 0.f};
  const int srow = tid >> 2;
  const int scol = (tid & 3) << 3;
  const ushort_t* ag = A + (size_t)(bm0 + srow) * Cc + scol;
  const ushort_t* bg = Bw + (size_t)(bn0 + srow) * Cc + scol;
  ushort_t* la = As + tid * 8;
  ushort_t* lb = Bs + tid * 8;
  const int frow = lane & 15;
  const int koff = (lane >> 4) << 3;
  for (int kt = 0; kt < Cc; kt += 32) {
    __syncthreads();
    __builtin_amdgcn_global_load_lds(GLP(ag + kt), LDSP(la), 16, 0, 0);
    __builtin_amdgcn_global_load_lds(GLP(ag + kt + 64 * Cc), LDSP(la + 2048), 16, 0, 0);
    __builtin_amdgcn_global_load_lds(GLP(bg + kt), LDSP(lb), 16, 0, 0);
    __builtin_amdgcn_global_load_lds(GLP(bg + kt + 64 * Cc), LDSP(lb + 2048), 16, 0, 0);
    __syncthreads();
    short8 af[4], bf[4];
#pragma unroll
    for (int i = 0; i < 4; i++)
      af[i] = *(const short8*)(As + (wm + i * 16 + frow) * 32 + koff);
#pragma unroll
    for (int j = 0; j < 4; j++)
      bf[j] = *(const short8*)(Bs + (wn + j * 16 + frow) * 32 + koff);
#pragma unroll
    for (int i = 0; i < 4; i++)
#pragma unroll
      for (int j = 0; j < 4; j++)
        acc[i][j] = __builtin_amdgcn_mfma_f32_16x16x32_bf16(af[i], bf[j], acc[i][j], 0, 0, 0);
  }
  const int mq = (lane >> 4) << 2;
  const int nl = lane & 15;
#pragma unroll
  for (int j = 0; j < 4; j++) {
    const int col = bn0 + wn + j * 16 + nl;
    const float bc = b2f(bias[col]);
#pragma unroll
    for (int i = 0; i < 4; i++) {
#pragma unroll
      for (int r = 0; r < 4; r++) {
        const int row = bm0 + wm + i * 16 + mq + r;
        Cout[(size_t)row * N1 + col] = f2b(acc[i][j][r] + bc);
      }
    }
  }
}

// ---------------------------------------------------------------- kernel 4
// wave-per-(sl,h): 3072 independent 16x16x64 attention problems per chunk.
// block = 4 waves, each wave owns one problem in its own LDS region.
__global__ __launch_bounds__(256) void attention_k(
    const ushort_t* __restrict__ qkvc, const ushort_t* __restrict__ qs,
    const ushort_t* __restrict__ qb, const ushort_t* __restrict__ ks,
    const ushort_t* __restrict__ kb, const ushort_t* __restrict__ relb,
    ushort_t* __restrict__ aoc) {
  __shared__ __align__(16) float qf[4][16][68];
  __shared__ __align__(16) float kf[4][16][68];
  __shared__ __align__(16) float vf[4][16][68];
  __shared__ __align__(16) float attw[4][16][20];
  __shared__ __align__(16) float lnw[4][64];   // qs,qb,ks,kb fp32
  const int tid = threadIdx.x;
  const int wave = tid >> 6;
  const int lane = tid & 63;
  if (tid < 64) {
    lnw[0][tid] = b2f(qs[tid]);
    lnw[1][tid] = b2f(qb[tid]);
    lnw[2][tid] = b2f(ks[tid]);
    lnw[3][tid] = b2f(kb[tid]);
  }
  const int p = blockIdx.x * 4 + wave;
  const int sl = p / 12;
  const int h = p - sl * 12;
  const ushort_t* src = qkvc + (size_t)sl * N1 + h * 192;
  // ---- load q,k,v (fp32) into this wave's LDS region
#pragma unroll
  for (int t = 0; t < 16; t++) {
    const ushort_t* r = src + (size_t)t * CH * N1;
    qf[wave][t][lane] = b2f(r[lane]);
    kf[wave][t][lane] = b2f(r[64 + lane]);
    vf[wave][t][lane] = b2f(r[128 + lane]);
  }
  __syncthreads();
  // ---- layernorm: 32 rows (16 q + 16 k), 2 lanes/row, 32 elems/lane
  {
    const int row = lane >> 1;
    const int half = lane & 1;
    float* buf = (row < 16) ? &qf[wave][row][0] : &kf[wave][row - 16][0];
    const float* sc = (row < 16) ? lnw[0] : lnw[2];
    const float* bi = (row < 16) ? lnw[1] : lnw[3];
    f32x4* bp = (f32x4*)(buf + half * 32);
    f32x4 v4[8];
    float s = 0.f;
#pragma unroll
    for (int q4 = 0; q4 < 8; q4++) {
      v4[q4] = bp[q4];
      s += v4[q4][0] + v4[q4][1] + v4[q4][2] + v4[q4][3];
    }
    s += __shfl_xor(s, 1);
    const float mu = s * (1.f / 64.f);
    float va = 0.f;
#pragma unroll
    for (int q4 = 0; q4 < 8; q4++) {
#pragma unroll
      for (int e = 0; e < 4; e++) {
        const float d = v4[q4][e] - mu;
        va += d * d;
      }
    }
    va += __shfl_xor(va, 1);
    const float rs = rsqrtf(va * (1.f / 64.f) + EPSV);
    const f32x4* sc4 = (const f32x4*)(sc + half * 32);
    const f32x4* bi4 = (const f32x4*)(bi + half * 32);
#pragma unroll
    for (int q4 = 0; q4 < 8; q4++) {
      f32x4 scv = sc4[q4], biv = bi4[q4], o;
#pragma unroll
      for (int e = 0; e < 4; e++) o[e] = (v4[q4][e] - mu) * rs * scv[e] + biv[e];
      bp[q4] = o;
    }
  }
  __syncthreads();
  // ---- scores + softmax: lane = g*16 + t2, g handles t1 = it*4+g
  const int g = lane >> 4;
  const int t2 = lane & 15;
#pragma unroll
  for (int it = 0; it < 4; it++) {
    const int t1 = it * 4 + g;
    const f32x4* qrow = (const f32x4*)&qf[wave][t1][0];
    const f32x4* krow = (const f32x4*)&kf[wave][t2][0];
    float sco = 0.f;
#pragma unroll
    for (int q4 = 0; q4 < 16; q4++) {
      f32x4 a = qrow[q4], b = krow[q4];
      sco += a[0] * b[0] + a[1] * b[1] + a[2] * b[2] + a[3] * b[3];
    }
    const int rp = t2 - t1;
    int bkt = (rp > 0) ? 16 : 0;
    const int n = (rp < 0) ? -rp : rp;
    if (n < 8) {
      bkt += n;
    } else {
      int vl = 8 + (int)(__logf((float)n * 0.125f) * 2.8853900817779268f);
      bkt += (vl < 15) ? vl : 15;
    }
    sco = sco * 0.125f + b2f(relb[bkt * NH + h]);
    float mx = sco;
#pragma unroll
    for (int m = 8; m >= 1; m >>= 1) mx = fmaxf(mx, __shfl_xor(mx, m));
    const float ex = __expf(sco - mx);
    float sm = ex;
#pragma unroll
    for (int m = 8; m >= 1; m >>= 1) sm += __shfl_xor(sm, m);
    attw[wave][t1][t2] = ex / sm;
  }
  __syncthreads();
  // ---- PV: group g handles t1 = it*4+g; 16 lanes cover j in 16B chunks
  const int jq = lane & 15;
#pragma unroll
  for (int it = 0; it < 4; it++) {
    const int t1 = it * 4 + g;
    const f32x4* arow = (const f32x4*)&attw[wave][t1][0];
    f32x4 o = (f32x4){0.f, 0.f, 0.f, 0.f};
#pragma unroll
    for (int tq = 0; tq < 4; tq++) {
      f32x4 aw = arow[tq];
#pragma unroll
      for (int e = 0; e < 4; e++) {
        f32x4 vv = *(const f32x4*)&vf[wave][tq * 4 + e][jq * 4];
        o[0] += aw[e] * vv[0];
        o[1] += aw[e] * vv[1];
        o[2] += aw[e] * vv[2];
        o[3] += aw[e] * vv[3];
      }
    }
    short4v st;
#pragma unroll
    for (int e = 0; e < 4; e++) st[e] = (short)f2b(o[e]);
    *(short4v*)(aoc + ((size_t)(t1 * CH + sl)) * Cc + h * HD + jq * 4) = st;
  }
}

// ---------------------------------------------------------------- kernel 5
// D[c_out][r] = wo[c_out][:] . aoc[r][:]; writes y[t][c_out][s0c+sl] f32,
// fused +bias +residual; global_load_lds staging
__global__ __launch_bounds__(256, 2) void gemm_out_k(
    const ushort_t* __restrict__ A, const ushort_t* __restrict__ Bm,
    const ushort_t* __restrict__ bias, const void* __restrict__ xres,
    const int* __restrict__ flag, float* __restrict__ y, int s0c) {
  __shared__ __align__(16) ushort_t As[128 * 32];
  __shared__ __align__(16) ushort_t Bs[128 * 32];
  const int isf32 = *flag;
  const int tid = threadIdx.x;
  const int bm0 = blockIdx.x * 128;  // c_out
  const int bn0 = blockIdx.y * 128;  // r (chunk row)
  const int lane = tid & 63;
  const int wave = tid >> 6;
  const int wm = (wave >> 1) << 6;
  const int wn = (wave & 1) << 6;
  f32x4 acc[4][4];
#pragma unroll
  for (int i = 0; i < 4; i++)
#pragma unroll
    for (int j = 0; j < 4; j++) acc[i][j] = (f32x4){0.f, 0.f, 0.f, 0.f};
  const int srow = tid >> 2;
  const int scol = (tid & 3) << 3;
  const ushort_t* ag = A + (size_t)(bm0 + srow) * Cc + scol;
  const ushort_t* bg = Bm + (size_t)(bn0 + srow) * Cc + scol;
  ushort_t* la = As + tid * 8;
  ushort_t* lb = Bs + tid * 8;
  const int frow = lane & 15;
  const int koff = (lane >> 4) << 3;
  for (int kt = 0; kt < Cc; kt += 32) {
    __syncthreads();
    __builtin_amdgcn_global_load_lds(GLP(ag + kt), LDSP(la), 16, 0, 0);
    __builtin_amdgcn_global_load_lds(GLP(ag + kt + 64 * Cc), LDSP(la + 2048), 16, 0, 0);
    __builtin_amdgcn_global_load_lds(GLP(bg + kt), LDSP(lb), 16, 0, 0);
    __builtin_amdgcn_global_load_lds(GLP(bg + kt + 64 * Cc), LDSP(lb + 2048), 16, 0, 0);
    __syncthreads();
    short8 af[4], bf[4];
#pragma unroll
    for (int i = 0; i < 4; i++)
      af[i] = *(const short8*)(As + (wm + i * 16 + frow) * 32 + koff);
#pragma unroll
    for (int j = 0; j < 4; j++)
      bf[j] = *(const short8*)(Bs + (wn + j * 16 + frow) * 32 + koff);
#pragma unroll
    for (int i = 0; i < 4; i++)
#pragma unroll
      for (int j = 0; j < 4; j++)
        acc[i][j] = __builtin_amdgcn_mfma_f32_16x16x32_bf16(af[i], bf[j], acc[i][j], 0, 0, 0);
  }
  const int mq = (lane >> 4) << 2;
  const int nl = lane & 15;
#pragma unroll
  for (int j = 0; j < 4; j++) {
    const int col = bn0 + wn + j * 16 + nl;  // chunk row r
    const int t = col >> 8;                  // r / CH
    const int sp = s0c + (col & (CH - 1));   // global spatial
#pragma unroll
    for (int i = 0; i < 4; i++) {
#pragma unroll
      for (int r = 0; r < 4; r++) {
        const int cch = bm0 + wm + i * 16 + mq + r;  // c_out
        const size_t off = ((size_t)(t * Cc + cch)) * Ss + sp;
        y[off] = acc[i][j][r] + b2f(bias[cch]) + load1(xres, off, isf32);
      }
    }
  }
}

// ----------------------------------------------------------------
extern "C" void kernel_launch(void* const* d_in, const int* in_sizes, int n_in,
                              void* d_out, int out_size, void* d_ws, size_t ws_size,
                              hipStream_t stream) {
  (void)in_sizes; (void)n_in; (void)out_size; (void)ws_size;
  const void* x   = d_in[0];
  const void* w1  = d_in[1];
  const void* win = d_in[2];
  const void* bin = d_in[3];
  const void* qsc = d_in[4];
  const void* qbi = d_in[5];
  const void* ksc = d_in[6];
  const void* kbi = d_in[7];
  const void* rbt = d_in[8];
  const void* wo  = d_in[9];
  const void* bo  = d_in[10];
  float* y = (float*)d_out;   // reference output dtype = float32

  char* ws = (char*)d_ws;
  int* flag      = (int*)ws;
  float* invrms  = (float*)(ws + 1024);
  ushort_t* smallw = (ushort_t*)(ws + 4096);
  ushort_t* w1b  = smallw;
  ushort_t* binb = smallw + 768;
  ushort_t* bob  = smallw + 3072;
  ushort_t* qsb  = smallw + 3840;
  ushort_t* qbb  = smallw + 3904;
  ushort_t* ksb  = smallw + 3968;
  ushort_t* kbb  = smallw + 4032;
  ushort_t* relbb = smallw + 4096;
  ushort_t* winb = (ushort_t*)(ws + 20480);
  ushort_t* wob  = (ushort_t*)(ws + 3559424);
  ushort_t* xnc  = (ushort_t*)(ws + 4739072);
  ushort_t* qkvc = (ushort_t*)(ws + 11030528);
  ushort_t* aoc  = (ushort_t*)(ws + 29904896);

  detect_k<<<1, 256, 0, stream>>>((const ushort_t*)x, flag);
  cvt_small_k<<<1, 256, 0, stream>>>(w1, bin, bo, qsc, qbi, ksc, kbi, rbt, smallw, flag);
  cvt_big_k<<<1769472 / 8 / 256, 256, 0, stream>>>(win, winb, 1769472 / 8, flag);
  cvt_big_k<<<589824 / 8 / 256, 256, 0, stream>>>(wo, wob, 589824 / 8, flag);
  rms_stats_k<<<dim3(Tt * NH), 256, 0, stream>>>(x, flag, invrms);
  for (int c8 = 0; c8 < NCH; c8++) {
    const int s0c = c8 * CH;
    norm_chunk_k<<<dim3(CH / 64, Cc / 64, Tt), 256, 0, stream>>>(x, flag, w1b, invrms, xnc, s0c);
    gemm_qkv_k<<<dim3(Mc / 128, N1 / 128), 256, 0, stream>>>(xnc, winb, binb, qkvc);
    attention_k<<<dim3(CH * NH / 4), 256, 0, stream>>>(qkvc, qsb, qbb, ksb, kbb, relbb, aoc);
    gemm_out_k<<<dim3(Cc / 128, Mc / 128), 256, 0, stream>>>(wob, aoc, bob, x, flag, y, s0c);
  }
}